// Round 1
// baseline (1140.166 us; speedup 1.0000x reference)
//
#include <hip/hip_runtime.h>
#include <hip/hip_bf16.h>

typedef __attribute__((ext_vector_type(4))) float f32x4;
typedef __attribute__((ext_vector_type(8))) __bf16 bf16x8;

// ---- helpers ----------------------------------------------------------------

__device__ inline unsigned short f2bf(float f) {
  union { float f; unsigned u; } x; x.f = f;
  unsigned r = x.u + 0x7fffu + ((x.u >> 16) & 1u);   // RNE
  return (unsigned short)(r >> 16);
}

// Stage a 128x64 bf16 tile (row-major, ldg elements) into LDS [128][72]
__device__ inline void stage_bf16_tile(const ushort* __restrict__ g, int ldg, ushort* l) {
  int tid = threadIdx.x;
#pragma unroll
  for (int t = 0; t < 4; ++t) {
    int c = tid + t * 256;            // 1024 chunks of 8 bf16
    int m = c >> 3, kc = (c & 7) << 3;
    *(int4*)(l + m * 72 + kc) = *(const int4*)(g + (size_t)m * ldg + kc);
  }
}

// Stage a 128x64 fp32 tile, converting to bf16, into LDS [128][72]
__device__ inline void stage_f32_tile(const float* __restrict__ g, int ldg, ushort* l) {
  int tid = threadIdx.x;
#pragma unroll
  for (int t = 0; t < 8; ++t) {
    int c = tid + t * 256;            // 2048 chunks of 4 floats
    int m = c >> 4, kc = (c & 15) << 2;
    float4 v = *(const float4*)(g + (size_t)m * ldg + kc);
    ushort4 o; o.x = f2bf(v.x); o.y = f2bf(v.y); o.z = f2bf(v.z); o.w = f2bf(v.w);
    *(ushort4*)(l + m * 72 + kc) = o;
  }
}

// One BK=64 step of 128x128 MFMA compute. lA: [128][72] (m,k), lB: [128][72] (n,k).
__device__ inline void mma_tile(const ushort* lA, const ushort* lB, f32x4 acc[4][4]) {
  int lane = threadIdx.x & 63, w = threadIdx.x >> 6;
  int wm = (w & 1) << 6, wn = (w >> 1) << 6;
  int row = lane & 15, quad = lane >> 4;
#pragma unroll
  for (int kk = 0; kk < 64; kk += 32) {
    bf16x8 a[4], b[4];
#pragma unroll
    for (int i = 0; i < 4; ++i)
      a[i] = *(const bf16x8*)(lA + (wm + i * 16 + row) * 72 + kk + quad * 8);
#pragma unroll
    for (int j = 0; j < 4; ++j)
      b[j] = *(const bf16x8*)(lB + (wn + j * 16 + row) * 72 + kk + quad * 8);
#pragma unroll
    for (int i = 0; i < 4; ++i)
#pragma unroll
      for (int j = 0; j < 4; ++j)
        acc[i][j] = __builtin_amdgcn_mfma_f32_16x16x32_bf16(a[i], b[j], acc[i][j], 0, 0, 0);
  }
}

// ---- prep kernels -----------------------------------------------------------

__global__ __launch_bounds__(256) void k_cvt_bf16(const float* __restrict__ in,
                                                  ushort* __restrict__ out, int n4) {
  int i = blockIdx.x * 256 + threadIdx.x;
  if (i >= n4) return;
  float4 v = *(const float4*)(in + (size_t)i * 4);
  ushort4 o; o.x = f2bf(v.x); o.y = f2bf(v.y); o.z = f2bf(v.z); o.w = f2bf(v.w);
  *(ushort4*)(out + (size_t)i * 4) = o;
}

// out[c][r] = bf16(in[r][c]); in is [R][C] fp32, out is [C][R] bf16
__global__ __launch_bounds__(256) void k_transpose_bf16(const float* __restrict__ in,
                                                        ushort* __restrict__ out, int R, int C) {
  __shared__ __align__(16) ushort t[64][72];
  int c0 = blockIdx.x << 6, r0 = blockIdx.y << 6;
  int tid = threadIdx.x;
#pragma unroll
  for (int it = 0; it < 4; ++it) {
    int idx = tid + it * 256;
    int r = idx >> 4, c4 = (idx & 15) << 2;
    float4 v = *(const float4*)(in + (size_t)(r0 + r) * C + c0 + c4);
    t[c4][r] = f2bf(v.x); t[c4 + 1][r] = f2bf(v.y);
    t[c4 + 2][r] = f2bf(v.z); t[c4 + 3][r] = f2bf(v.w);
  }
  __syncthreads();
#pragma unroll
  for (int it = 0; it < 4; ++it) {
    int idx = tid + it * 256;
    int c = idx >> 4, r4 = (idx & 15) << 2;
    ushort4 o; o.x = t[c][r4]; o.y = t[c][r4 + 1]; o.z = t[c][r4 + 2]; o.w = t[c][r4 + 3];
    *(ushort4*)(out + (size_t)(c0 + c) * R + r0 + r4) = o;
  }
}

// ---- QKV GEMM: [4096,2048] x [2048,6144] ------------------------------------
// qh[bh][n][d] = q/sqrt(D), kh[bh][n][d] = k, vt[bh][d][n] = v (transposed)
__global__ __launch_bounds__(256) void k_qkv(const ushort* __restrict__ A,
                                             const ushort* __restrict__ Bt,
                                             ushort* __restrict__ qh,
                                             ushort* __restrict__ kh,
                                             ushort* __restrict__ vt) {
  __shared__ __align__(16) ushort lA[128 * 72];
  __shared__ __align__(16) ushort lB[128 * 72];
  int rt = blockIdx.x, ct = blockIdx.y;
  f32x4 z = {0.f, 0.f, 0.f, 0.f};
  f32x4 acc[4][4];
#pragma unroll
  for (int i = 0; i < 4; ++i)
#pragma unroll
    for (int j = 0; j < 4; ++j) acc[i][j] = z;
  for (int kt = 0; kt < 2048; kt += 64) {
    __syncthreads();
    stage_bf16_tile(A + (size_t)rt * 128 * 2048 + kt, 2048, lA);
    stage_bf16_tile(Bt + (size_t)ct * 128 * 2048 + kt, 2048, lB);
    __syncthreads();
    mma_tile(lA, lB, acc);
  }
  int lane = threadIdx.x & 63, w = threadIdx.x >> 6;
  int wm = (w & 1) << 6, wn = (w >> 1) << 6;
  int col = lane & 15, rb = (lane >> 4) << 2;
#pragma unroll
  for (int i = 0; i < 4; ++i)
#pragma unroll
    for (int j = 0; j < 4; ++j)
#pragma unroll
      for (int r = 0; r < 4; ++r) {
        int R = rt * 128 + wm + i * 16 + rb + r;
        int C = ct * 128 + wn + j * 16 + col;
        int b = R >> 11, n = R & 2047;
        int seg = C >> 11, hh = (C >> 7) & 15, d = C & 127;
        int bh = b * 16 + hh;
        float v = acc[i][j][r];
        if (seg == 0)      qh[((size_t)bh * 2048 + n) * 128 + d] = f2bf(v * 0.08838834764831845f);
        else if (seg == 1) kh[((size_t)bh * 2048 + n) * 128 + d] = f2bf(v);
        else               vt[((size_t)bh * 128 + d) * 2048 + n] = f2bf(v);
      }
}

// ---- scores: S[bh][n][m] = q . k, lower-triangle tiles only -----------------
__global__ __launch_bounds__(256) void k_scores(const ushort* __restrict__ qh,
                                                const ushort* __restrict__ kh,
                                                float* __restrict__ sc) {
  int rt = blockIdx.x, ct = blockIdx.y, bh = blockIdx.z;
  if (ct > rt) return;
  __shared__ __align__(16) ushort lA[128 * 72];
  __shared__ __align__(16) ushort lB[128 * 72];
  f32x4 z = {0.f, 0.f, 0.f, 0.f};
  f32x4 acc[4][4];
#pragma unroll
  for (int i = 0; i < 4; ++i)
#pragma unroll
    for (int j = 0; j < 4; ++j) acc[i][j] = z;
  const ushort* Ab = qh + (size_t)bh * 2048 * 128 + (size_t)rt * 128 * 128;
  const ushort* Bb = kh + (size_t)bh * 2048 * 128 + (size_t)ct * 128 * 128;
#pragma unroll
  for (int kt = 0; kt < 128; kt += 64) {
    __syncthreads();
    stage_bf16_tile(Ab + kt, 128, lA);
    stage_bf16_tile(Bb + kt, 128, lB);
    __syncthreads();
    mma_tile(lA, lB, acc);
  }
  float* base = sc + (size_t)bh * 2048 * 2048;
  int lane = threadIdx.x & 63, w = threadIdx.x >> 6;
  int wm = (w & 1) << 6, wn = (w >> 1) << 6;
  int col = lane & 15, rb = (lane >> 4) << 2;
#pragma unroll
  for (int i = 0; i < 4; ++i)
#pragma unroll
    for (int j = 0; j < 4; ++j)
#pragma unroll
      for (int r = 0; r < 4; ++r) {
        int R = rt * 128 + wm + i * 16 + rb + r;
        int C = ct * 128 + wn + j * 16 + col;
        base[(size_t)R * 2048 + C] = acc[i][j][r];
      }
}

// ---- row softmax with causal mask, in place over d_out attn region ----------
__global__ __launch_bounds__(256) void k_softmax(float* __restrict__ sc) {
  int row = blockIdx.x;          // bh*2048 + n
  int n = row & 2047;
  float* p = sc + (size_t)row * 2048;
  int tid = threadIdx.x;
  float vals[8];
  float mx = -INFINITY;
#pragma unroll
  for (int t = 0; t < 2; ++t) {
    float4 v = *(const float4*)(p + t * 1024 + tid * 4);
    float vv[4] = {v.x, v.y, v.z, v.w};
#pragma unroll
    for (int i = 0; i < 4; ++i) {
      int m = t * 1024 + tid * 4 + i;
      float x = (m <= n) ? vv[i] : -INFINITY;
      vals[t * 4 + i] = x;
      mx = fmaxf(mx, x);
    }
  }
#pragma unroll
  for (int o = 32; o > 0; o >>= 1) mx = fmaxf(mx, __shfl_xor(mx, o));
  __shared__ float red[4];
  if ((tid & 63) == 0) red[tid >> 6] = mx;
  __syncthreads();
  mx = fmaxf(fmaxf(red[0], red[1]), fmaxf(red[2], red[3]));
  float s = 0.f;
#pragma unroll
  for (int e = 0; e < 8; ++e) { float ev = expf(vals[e] - mx); vals[e] = ev; s += ev; }
#pragma unroll
  for (int o = 32; o > 0; o >>= 1) s += __shfl_xor(s, o);
  __syncthreads();
  if ((tid & 63) == 0) red[tid >> 6] = s;
  __syncthreads();
  float inv = 1.f / (red[0] + red[1] + red[2] + red[3]);
#pragma unroll
  for (int t = 0; t < 2; ++t) {
    float4 v;
    v.x = vals[t * 4 + 0] * inv; v.y = vals[t * 4 + 1] * inv;
    v.z = vals[t * 4 + 2] * inv; v.w = vals[t * 4 + 3] * inv;
    *(float4*)(p + t * 1024 + tid * 4) = v;
  }
}

// ---- attn_out = P . V -------------------------------------------------------
// Ao[b][n][h*128+d] bf16
__global__ __launch_bounds__(256) void k_pv(const float* __restrict__ sc,
                                            const ushort* __restrict__ vt,
                                            ushort* __restrict__ Ao) {
  int rt = blockIdx.x, bh = blockIdx.y;
  __shared__ __align__(16) ushort lA[128 * 72];
  __shared__ __align__(16) ushort lB[128 * 72];
  f32x4 z = {0.f, 0.f, 0.f, 0.f};
  f32x4 acc[4][4];
#pragma unroll
  for (int i = 0; i < 4; ++i)
#pragma unroll
    for (int j = 0; j < 4; ++j) acc[i][j] = z;
  const float* Pb = sc + (size_t)bh * 2048 * 2048 + (size_t)rt * 128 * 2048;
  const ushort* Vb = vt + (size_t)bh * 128 * 2048;
  int kend = (rt + 1) * 128;
  for (int kt = 0; kt < kend; kt += 64) {
    __syncthreads();
    stage_f32_tile(Pb + kt, 2048, lA);
    stage_bf16_tile(Vb + kt, 2048, lB);
    __syncthreads();
    mma_tile(lA, lB, acc);
  }
  int b = bh >> 4, hh = bh & 15;
  int lane = threadIdx.x & 63, w = threadIdx.x >> 6;
  int wm = (w & 1) << 6, wn = (w >> 1) << 6;
  int col = lane & 15, rb = (lane >> 4) << 2;
#pragma unroll
  for (int i = 0; i < 4; ++i)
#pragma unroll
    for (int j = 0; j < 4; ++j)
#pragma unroll
      for (int r = 0; r < 4; ++r) {
        int R = rt * 128 + wm + i * 16 + rb + r;   // token n
        int C = wn + j * 16 + col;                 // d in [0,128)
        Ao[((size_t)b * 2048 + R) * 2048 + hh * 128 + C] = f2bf(acc[i][j][r]);
      }
}

// ---- out = Ao @ w_proj + b_proj --------------------------------------------
__global__ __launch_bounds__(256) void k_proj(const ushort* __restrict__ Ao,
                                              const ushort* __restrict__ Wt,
                                              const float* __restrict__ bias,
                                              float* __restrict__ out) {
  int rt = blockIdx.x, ct = blockIdx.y;
  __shared__ __align__(16) ushort lA[128 * 72];
  __shared__ __align__(16) ushort lB[128 * 72];
  f32x4 z = {0.f, 0.f, 0.f, 0.f};
  f32x4 acc[4][4];
#pragma unroll
  for (int i = 0; i < 4; ++i)
#pragma unroll
    for (int j = 0; j < 4; ++j) acc[i][j] = z;
  for (int kt = 0; kt < 2048; kt += 64) {
    __syncthreads();
    stage_bf16_tile(Ao + (size_t)rt * 128 * 2048 + kt, 2048, lA);
    stage_bf16_tile(Wt + (size_t)ct * 128 * 2048 + kt, 2048, lB);
    __syncthreads();
    mma_tile(lA, lB, acc);
  }
  int lane = threadIdx.x & 63, w = threadIdx.x >> 6;
  int wm = (w & 1) << 6, wn = (w >> 1) << 6;
  int col = lane & 15, rb = (lane >> 4) << 2;
#pragma unroll
  for (int i = 0; i < 4; ++i)
#pragma unroll
    for (int j = 0; j < 4; ++j)
#pragma unroll
      for (int r = 0; r < 4; ++r) {
        int R = rt * 128 + wm + i * 16 + rb + r;
        int C = ct * 128 + wn + j * 16 + col;
        out[(size_t)R * 2048 + C] = acc[i][j][r] + bias[C];
      }
}

// ---- launch -----------------------------------------------------------------

extern "C" void kernel_launch(void* const* d_in, const int* in_sizes, int n_in,
                              void* d_out, int out_size, void* d_ws, size_t ws_size,
                              hipStream_t stream) {
  const float* hs = (const float*)d_in[0];   // [2,2048,2048]
  const float* wf = (const float*)d_in[1];   // [2048,6144]
  const float* wp = (const float*)d_in[2];   // [2048,2048]
  const float* bp = (const float*)d_in[3];   // [2048]
  float* out = (float*)d_out;                // [2,2048,2048]
  float* attnw = out + (size_t)8388608;      // [2,16,2048,2048]

  ushort* Hb  = (ushort*)d_ws;               // 4096x2048 bf16
  ushort* Wft = Hb  + (size_t)8388608;       // 6144x2048 bf16 (w_fused^T)
  ushort* Wpt = Wft + (size_t)12582912;      // 2048x2048 bf16 (w_proj^T)
  ushort* qh  = Wpt + (size_t)4194304;       // [32][2048][128] bf16, pre-scaled
  ushort* kh  = qh  + (size_t)8388608;       // [32][2048][128] bf16
  ushort* vt  = kh  + (size_t)8388608;       // [32][128][2048] bf16 (V^T)
  ushort* Ao  = vt  + (size_t)8388608;       // [4096][2048] bf16

  k_cvt_bf16<<<8192, 256, 0, stream>>>(hs, Hb, 2097152);
  k_transpose_bf16<<<dim3(96, 32), 256, 0, stream>>>(wf, Wft, 2048, 6144);
  k_transpose_bf16<<<dim3(32, 32), 256, 0, stream>>>(wp, Wpt, 2048, 2048);
  k_qkv<<<dim3(32, 48), 256, 0, stream>>>(Hb, Wft, qh, kh, vt);
  k_scores<<<dim3(16, 16, 32), 256, 0, stream>>>(qh, kh, attnw);
  k_softmax<<<65536, 256, 0, stream>>>(attnw);
  k_pv<<<dim3(16, 32), 256, 0, stream>>>(attnw, vt, Ao);
  k_proj<<<dim3(32, 16), 256, 0, stream>>>(Ao, Wpt, bp, out);
}

// Round 2
// 1129.986 us; speedup vs baseline: 1.0090x; 1.0090x over previous
//
#include <hip/hip_runtime.h>
#include <hip/hip_bf16.h>

typedef __attribute__((ext_vector_type(4))) float f32x4;
typedef __attribute__((ext_vector_type(8))) __bf16 bf16x8;

// ---- helpers ----------------------------------------------------------------

__device__ inline unsigned short f2bf(float f) {
  union { float f; unsigned u; } x; x.f = f;
  unsigned r = x.u + 0x7fffu + ((x.u >> 16) & 1u);   // RNE
  return (unsigned short)(r >> 16);
}

// Stage a 128x64 bf16 tile (row-major, ldg elements) into LDS [128][72]
__device__ inline void stage_bf16_tile(const ushort* __restrict__ g, int ldg, ushort* l) {
  int tid = threadIdx.x;
#pragma unroll
  for (int t = 0; t < 4; ++t) {
    int c = tid + t * 256;            // 1024 chunks of 8 bf16
    int m = c >> 3, kc = (c & 7) << 3;
    *(int4*)(l + m * 72 + kc) = *(const int4*)(g + (size_t)m * ldg + kc);
  }
}

// One BK=64 step of 128x128 MFMA compute. lA: [128][72] (m,k), lB: [128][72] (n,k).
__device__ inline void mma_tile(const ushort* lA, const ushort* lB, f32x4 acc[4][4]) {
  int lane = threadIdx.x & 63, w = threadIdx.x >> 6;
  int wm = (w & 1) << 6, wn = (w >> 1) << 6;
  int row = lane & 15, quad = lane >> 4;
#pragma unroll
  for (int kk = 0; kk < 64; kk += 32) {
    bf16x8 a[4], b[4];
#pragma unroll
    for (int i = 0; i < 4; ++i)
      a[i] = *(const bf16x8*)(lA + (wm + i * 16 + row) * 72 + kk + quad * 8);
#pragma unroll
    for (int j = 0; j < 4; ++j)
      b[j] = *(const bf16x8*)(lB + (wn + j * 16 + row) * 72 + kk + quad * 8);
#pragma unroll
    for (int i = 0; i < 4; ++i)
#pragma unroll
      for (int j = 0; j < 4; ++j)
        acc[i][j] = __builtin_amdgcn_mfma_f32_16x16x32_bf16(a[i], b[j], acc[i][j], 0, 0, 0);
  }
}

// PV step: A-frags from lP [128][136] (t, s), B-frags from lV [128][72] (d, s).
__device__ inline void mma_pv(const ushort* lP, const ushort* lV, int kk2, f32x4 acc[4][4]) {
  int lane = threadIdx.x & 63, w = threadIdx.x >> 6;
  int wm = (w & 1) << 6, wn = (w >> 1) << 6;
  int row = lane & 15, quad = lane >> 4;
#pragma unroll
  for (int kk = 0; kk < 64; kk += 32) {
    bf16x8 a[4], b[4];
#pragma unroll
    for (int i = 0; i < 4; ++i)
      a[i] = *(const bf16x8*)(lP + (wm + i * 16 + row) * 136 + kk2 * 64 + kk + quad * 8);
#pragma unroll
    for (int j = 0; j < 4; ++j)
      b[j] = *(const bf16x8*)(lV + (wn + j * 16 + row) * 72 + kk + quad * 8);
#pragma unroll
    for (int i = 0; i < 4; ++i)
#pragma unroll
      for (int j = 0; j < 4; ++j)
        acc[i][j] = __builtin_amdgcn_mfma_f32_16x16x32_bf16(a[i], b[j], acc[i][j], 0, 0, 0);
  }
}

// ---- prep kernels -----------------------------------------------------------

__global__ __launch_bounds__(256) void k_cvt_bf16(const float* __restrict__ in,
                                                  ushort* __restrict__ out, int n4) {
  int i = blockIdx.x * 256 + threadIdx.x;
  if (i >= n4) return;
  float4 v = *(const float4*)(in + (size_t)i * 4);
  ushort4 o; o.x = f2bf(v.x); o.y = f2bf(v.y); o.z = f2bf(v.z); o.w = f2bf(v.w);
  *(ushort4*)(out + (size_t)i * 4) = o;
}

// out[c][r] = bf16(in[r][c]); in is [R][C] fp32, out is [C][R] bf16
__global__ __launch_bounds__(256) void k_transpose_bf16(const float* __restrict__ in,
                                                        ushort* __restrict__ out, int R, int C) {
  __shared__ __align__(16) ushort t[64][72];
  int c0 = blockIdx.x << 6, r0 = blockIdx.y << 6;
  int tid = threadIdx.x;
#pragma unroll
  for (int it = 0; it < 4; ++it) {
    int idx = tid + it * 256;
    int r = idx >> 4, c4 = (idx & 15) << 2;
    float4 v = *(const float4*)(in + (size_t)(r0 + r) * C + c0 + c4);
    t[c4][r] = f2bf(v.x); t[c4 + 1][r] = f2bf(v.y);
    t[c4 + 2][r] = f2bf(v.z); t[c4 + 3][r] = f2bf(v.w);
  }
  __syncthreads();
#pragma unroll
  for (int it = 0; it < 4; ++it) {
    int idx = tid + it * 256;
    int c = idx >> 4, r4 = (idx & 15) << 2;
    ushort4 o; o.x = t[c][r4]; o.y = t[c][r4 + 1]; o.z = t[c][r4 + 2]; o.w = t[c][r4 + 3];
    *(ushort4*)(out + (size_t)(c0 + c) * R + r0 + r4) = o;
  }
}

// ---- QKV GEMM: [4096,2048] x [2048,6144] ------------------------------------
// qh[bh][n][d] = q/sqrt(D), kh[bh][n][d] = k, vt[bh][d][n] = v (transposed)
__global__ __launch_bounds__(256) void k_qkv(const ushort* __restrict__ A,
                                             const ushort* __restrict__ Bt,
                                             ushort* __restrict__ qh,
                                             ushort* __restrict__ kh,
                                             ushort* __restrict__ vt) {
  __shared__ __align__(16) ushort lA[128 * 72];
  __shared__ __align__(16) ushort lB[128 * 72];
  int rt = blockIdx.x, ct = blockIdx.y;
  f32x4 z = {0.f, 0.f, 0.f, 0.f};
  f32x4 acc[4][4];
#pragma unroll
  for (int i = 0; i < 4; ++i)
#pragma unroll
    for (int j = 0; j < 4; ++j) acc[i][j] = z;
  for (int kt = 0; kt < 2048; kt += 64) {
    __syncthreads();
    stage_bf16_tile(A + (size_t)rt * 128 * 2048 + kt, 2048, lA);
    stage_bf16_tile(Bt + (size_t)ct * 128 * 2048 + kt, 2048, lB);
    __syncthreads();
    mma_tile(lA, lB, acc);
  }
  int lane = threadIdx.x & 63, w = threadIdx.x >> 6;
  int wm = (w & 1) << 6, wn = (w >> 1) << 6;
  int col = lane & 15, rb = (lane >> 4) << 2;
#pragma unroll
  for (int i = 0; i < 4; ++i)
#pragma unroll
    for (int j = 0; j < 4; ++j)
#pragma unroll
      for (int r = 0; r < 4; ++r) {
        int R = rt * 128 + wm + i * 16 + rb + r;
        int C = ct * 128 + wn + j * 16 + col;
        int b = R >> 11, n = R & 2047;
        int seg = C >> 11, hh = (C >> 7) & 15, d = C & 127;
        int bh = b * 16 + hh;
        float v = acc[i][j][r];
        if (seg == 0)      qh[((size_t)bh * 2048 + n) * 128 + d] = f2bf(v * 0.08838834764831845f);
        else if (seg == 1) kh[((size_t)bh * 2048 + n) * 128 + d] = f2bf(v);
        else               vt[((size_t)bh * 128 + d) * 2048 + n] = f2bf(v);
      }
}

// ---- fused attention middle: scores + softmax + PV --------------------------
// Phase 1: online row stats (m, l) over causal tiles via MFMA (no writes).
// Phase 2: recompute S, write normalized P fp32 to attnw, PV-accumulate via LDS
//          bf16 round-trip. Upper-triangle tiles zero-filled coalesced.
__global__ __launch_bounds__(256, 2) void k_attn(const ushort* __restrict__ qh,
                                                 const ushort* __restrict__ kh,
                                                 const ushort* __restrict__ vt,
                                                 float* __restrict__ attnw,
                                                 ushort* __restrict__ Ao) {
  __shared__ __align__(16) ushort lAB[2 * 128 * 72];   // lA|lB, reused as lP [128][136]
  __shared__ __align__(16) ushort lV[128 * 72];
  __shared__ float mArr[128], lArr[128], invA[128], tm0[128], tm1[128];

  int id = blockIdx.x;
  int r5 = id & 31, p = r5 >> 1;
  int rt = (r5 & 1) ? p : 15 - p;                      // heavy/light interleave
  int bh = ((id >> 5) << 1) | ((id >> 4) & 1);

  ushort* lA = lAB;
  ushort* lB = lAB + 128 * 72;
  int tid = threadIdx.x;
  int lane = tid & 63, w = tid >> 6;
  int wm = (w & 1) << 6, wn = (w >> 1) << 6;
  int c16 = lane & 15, quad = lane >> 4;

  const ushort* Qb = qh + ((size_t)bh * 2048 + rt * 128) * 128;
  const ushort* Kb = kh + (size_t)bh * 2048 * 128;
  const ushort* Vb = vt + (size_t)bh * 128 * 2048;
  float* Pg = attnw + (size_t)bh * 2048 * 2048 + (size_t)rt * 128 * 2048;

  if (tid < 128) { mArr[tid] = -INFINITY; lArr[tid] = 0.f; }
  __syncthreads();

  f32x4 z = {0.f, 0.f, 0.f, 0.f};
  float* tmw = (wn == 0) ? tm0 : tm1;

  // ---- phase 1: stats ----
  for (int ct = 0; ct <= rt; ++ct) {
    f32x4 acc[4][4];
#pragma unroll
    for (int i = 0; i < 4; ++i)
#pragma unroll
      for (int j = 0; j < 4; ++j) acc[i][j] = z;
#pragma unroll
    for (int kt = 0; kt < 128; kt += 64) {
      __syncthreads();
      stage_bf16_tile(Qb + kt, 128, lA);
      stage_bf16_tile(Kb + (size_t)ct * 128 * 128 + kt, 128, lB);
      __syncthreads();
      mma_tile(lA, lB, acc);
    }
    bool diag = (ct == rt);
    // per-row tile max
#pragma unroll
    for (int i = 0; i < 4; ++i)
#pragma unroll
      for (int r = 0; r < 4; ++r) {
        int lr = wm + i * 16 + quad * 4 + r;
        float mx = -INFINITY;
#pragma unroll
        for (int j = 0; j < 4; ++j) {
          int lc = wn + j * 16 + c16;
          if (!diag || lc <= lr) mx = fmaxf(mx, acc[i][j][r]);
        }
#pragma unroll
        for (int o = 1; o < 16; o <<= 1) mx = fmaxf(mx, __shfl_xor(mx, o));
        if (c16 == 0) tmw[lr] = mx;
      }
    __syncthreads();
    if (tid < 128) {
      float tmax = fmaxf(tm0[tid], tm1[tid]);
      float mo = mArr[tid];
      float mn = fmaxf(mo, tmax);
      float corr = (mo == -INFINITY) ? 0.f : __expf(mo - mn);
      mArr[tid] = mn;
      lArr[tid] *= corr;
    }
    __syncthreads();
    // per-row tile sum of exp
#pragma unroll
    for (int i = 0; i < 4; ++i)
#pragma unroll
      for (int r = 0; r < 4; ++r) {
        int lr = wm + i * 16 + quad * 4 + r;
        float mn = mArr[lr];
        float s = 0.f;
#pragma unroll
        for (int j = 0; j < 4; ++j) {
          int lc = wn + j * 16 + c16;
          if (!diag || lc <= lr) s += __expf(acc[i][j][r] - mn);
        }
#pragma unroll
        for (int o = 1; o < 16; o <<= 1) s += __shfl_xor(s, o);
        if (c16 == 0) tmw[lr] = s;     // tm reused as partial-sum slot
      }
    __syncthreads();
    if (tid < 128) lArr[tid] += tm0[tid] + tm1[tid];
  }
  __syncthreads();
  if (tid < 128) invA[tid] = 1.f / lArr[tid];
  __syncthreads();

  // ---- phase 2: recompute S, write P, accumulate PV ----
  f32x4 o2[4][4];
#pragma unroll
  for (int i = 0; i < 4; ++i)
#pragma unroll
    for (int j = 0; j < 4; ++j) o2[i][j] = z;

  for (int ct = 0; ct <= rt; ++ct) {
    f32x4 acc[4][4];
#pragma unroll
    for (int i = 0; i < 4; ++i)
#pragma unroll
      for (int j = 0; j < 4; ++j) acc[i][j] = z;
#pragma unroll
    for (int kt = 0; kt < 128; kt += 64) {
      __syncthreads();
      stage_bf16_tile(Qb + kt, 128, lA);
      stage_bf16_tile(Kb + (size_t)ct * 128 * 128 + kt, 128, lB);
      __syncthreads();
      mma_tile(lA, lB, acc);
    }
    __syncthreads();                       // done reading lA/lB -> reuse as lP
    bool diag = (ct == rt);
    ushort* lP = lAB;
#pragma unroll
    for (int i = 0; i < 4; ++i)
#pragma unroll
      for (int r = 0; r < 4; ++r) {
        int lr = wm + i * 16 + quad * 4 + r;
        float mn = mArr[lr], inv = invA[lr];
        float* prow = Pg + (size_t)lr * 2048 + ct * 128;
#pragma unroll
        for (int j = 0; j < 4; ++j) {
          int lc = wn + j * 16 + c16;
          float e = (!diag || lc <= lr) ? __expf(acc[i][j][r] - mn) * inv : 0.f;
          lP[lr * 136 + lc] = f2bf(e);
          prow[lc] = e;
        }
      }
    stage_bf16_tile(Vb + ct * 128, 2048, lV);
    __syncthreads();
    mma_pv(lP, lV, 0, o2);
    __syncthreads();
    stage_bf16_tile(Vb + ct * 128 + 64, 2048, lV);
    __syncthreads();
    mma_pv(lP, lV, 1, o2);
  }

  // zero upper-triangle tiles (coalesced)
  float4 z4 = make_float4(0.f, 0.f, 0.f, 0.f);
  for (int ct = rt + 1; ct < 16; ++ct) {
    float* T = Pg + ct * 128;
#pragma unroll
    for (int it = 0; it < 16; ++it) {
      int idx = tid + it * 256;
      int rr = idx >> 5, cc = (idx & 31) << 2;
      *(float4*)(T + (size_t)rr * 2048 + cc) = z4;
    }
  }

  // O epilogue -> Ao[b][n][h*128+d]
  int b = bh >> 4, hh = bh & 15;
#pragma unroll
  for (int i = 0; i < 4; ++i)
#pragma unroll
    for (int j = 0; j < 4; ++j)
#pragma unroll
      for (int r = 0; r < 4; ++r) {
        int R = rt * 128 + wm + i * 16 + quad * 4 + r;
        int C = wn + j * 16 + c16;
        Ao[((size_t)b * 2048 + R) * 2048 + hh * 128 + C] = f2bf(o2[i][j][r]);
      }
}

// ---- out = Ao @ w_proj + b_proj --------------------------------------------
__global__ __launch_bounds__(256) void k_proj(const ushort* __restrict__ Ao,
                                              const ushort* __restrict__ Wt,
                                              const float* __restrict__ bias,
                                              float* __restrict__ out) {
  int rt = blockIdx.x, ct = blockIdx.y;
  __shared__ __align__(16) ushort lA[128 * 72];
  __shared__ __align__(16) ushort lB[128 * 72];
  f32x4 z = {0.f, 0.f, 0.f, 0.f};
  f32x4 acc[4][4];
#pragma unroll
  for (int i = 0; i < 4; ++i)
#pragma unroll
    for (int j = 0; j < 4; ++j) acc[i][j] = z;
  for (int kt = 0; kt < 2048; kt += 64) {
    __syncthreads();
    stage_bf16_tile(Ao + (size_t)rt * 128 * 2048 + kt, 2048, lA);
    stage_bf16_tile(Wt + (size_t)ct * 128 * 2048 + kt, 2048, lB);
    __syncthreads();
    mma_tile(lA, lB, acc);
  }
  int lane = threadIdx.x & 63, w = threadIdx.x >> 6;
  int wm = (w & 1) << 6, wn = (w >> 1) << 6;
  int col = lane & 15, rb = (lane >> 4) << 2;
#pragma unroll
  for (int i = 0; i < 4; ++i)
#pragma unroll
    for (int j = 0; j < 4; ++j)
#pragma unroll
      for (int r = 0; r < 4; ++r) {
        int R = rt * 128 + wm + i * 16 + rb + r;
        int C = ct * 128 + wn + j * 16 + col;
        out[(size_t)R * 2048 + C] = acc[i][j][r] + bias[C];
      }
}

// ---- launch -----------------------------------------------------------------

extern "C" void kernel_launch(void* const* d_in, const int* in_sizes, int n_in,
                              void* d_out, int out_size, void* d_ws, size_t ws_size,
                              hipStream_t stream) {
  const float* hs = (const float*)d_in[0];   // [2,2048,2048]
  const float* wf = (const float*)d_in[1];   // [2048,6144]
  const float* wp = (const float*)d_in[2];   // [2048,2048]
  const float* bp = (const float*)d_in[3];   // [2048]
  float* out = (float*)d_out;                // [2,2048,2048]
  float* attnw = out + (size_t)8388608;      // [2,16,2048,2048]

  ushort* Hb  = (ushort*)d_ws;               // 4096x2048 bf16
  ushort* Wft = Hb  + (size_t)8388608;       // 6144x2048 bf16 (w_fused^T)
  ushort* Wpt = Wft + (size_t)12582912;      // 2048x2048 bf16 (w_proj^T)
  ushort* qh  = Wpt + (size_t)4194304;       // [32][2048][128] bf16, pre-scaled
  ushort* kh  = qh  + (size_t)8388608;       // [32][2048][128] bf16
  ushort* vt  = kh  + (size_t)8388608;       // [32][128][2048] bf16 (V^T)
  ushort* Ao  = vt  + (size_t)8388608;       // [4096][2048] bf16

  k_cvt_bf16<<<8192, 256, 0, stream>>>(hs, Hb, 2097152);
  k_transpose_bf16<<<dim3(96, 32), 256, 0, stream>>>(wf, Wft, 2048, 6144);
  k_transpose_bf16<<<dim3(32, 32), 256, 0, stream>>>(wp, Wpt, 2048, 2048);
  k_qkv<<<dim3(32, 48), 256, 0, stream>>>(Hb, Wft, qh, kh, vt);
  k_attn<<<512, 256, 0, stream>>>(qh, kh, vt, attnw, Ao);
  k_proj<<<dim3(32, 16), 256, 0, stream>>>(Ao, Wpt, bp, out);
}